// Round 1
// baseline (1043.685 us; speedup 1.0000x reference)
//
#include <hip/hip_runtime.h>
#include <hip/hip_bf16.h>
#include <stdint.h>

#define NN   100000   // nodes per type
#define EE   600000   // edges per type
#define HH   128      // hidden
#define OUTC 64       // out channels

typedef __attribute__((ext_vector_type(8))) short bf16x8;   // 8 bf16 in 4 VGPRs
typedef __attribute__((ext_vector_type(4))) float f32x4;

__device__ __forceinline__ float bfbits2f(unsigned short b) {
    union { unsigned u; float f; } v; v.u = ((unsigned)b) << 16; return v.f;
}
__device__ __forceinline__ unsigned short f2bfbits(float f) {
    union { float f; unsigned u; } v; v.f = f;
    unsigned r = v.u + 0x7fffu + ((v.u >> 16) & 1u);   // RNE
    return (unsigned short)(r >> 16);
}

// ---------------------------------------------------------------------------
// Vectorized f32 -> bf16: 8 elems/thread (32B in, 16B out). n must be %8==0.
// ---------------------------------------------------------------------------
__global__ __launch_bounds__(256) void cvt_f32_bf16_v8(
    const float* __restrict__ in, unsigned short* __restrict__ out, int n8)
{
    int i = blockIdx.x * 256 + threadIdx.x;
    if (i >= n8) return;
    f32x4 a = ((const f32x4*)in)[(size_t)i * 2];
    f32x4 b = ((const f32x4*)in)[(size_t)i * 2 + 1];
    union { unsigned short us[8]; uint4 u4; } r;
    for (int j = 0; j < 4; ++j) { r.us[j] = f2bfbits(a[j]); r.us[4 + j] = f2bfbits(b[j]); }
    ((uint4*)out)[i] = r.u4;
}

// ---------------------------------------------------------------------------
// Linked-list adjacency build, all 4 edge types in one pass.
// ---------------------------------------------------------------------------
__global__ __launch_bounds__(256) void build_ll(
    const int* __restrict__ ei0, const int* __restrict__ ei1,
    const int* __restrict__ ei2, const int* __restrict__ ei3,
    int* __restrict__ head,      // [4*NN], pre-init to -1
    int2* __restrict__ node)     // [4*EE]
{
    int gid = blockIdx.x * 256 + threadIdx.x;
    if (gid >= 4 * EE) return;
    int t = gid / EE, e = gid - t * EE;
    const int* ei = (t == 0) ? ei0 : (t == 1) ? ei1 : (t == 2) ? ei2 : ei3;
    int src = ei[e];
    int dst = ei[EE + e];
    int prev = atomicExch(&head[t * NN + dst], gid);
    node[gid] = make_int2(src, prev);
}

// ---------------------------------------------------------------------------
// Gather-mean, bf16 source, TWO rows per wave (half-wave per row).
// Lane l of each half covers feats [4l, 4l+3] (uint2 = 8B per hop).
// Two independent list chases per wave double latency hiding.
// ---------------------------------------------------------------------------
__global__ __launch_bounds__(256) void gather_ll2(
    const int* __restrict__ head,            // head + t*NN
    const int2* __restrict__ node,           // global edge-slot array
    const unsigned short* __restrict__ xsrc, // [NN*HH] bf16
    unsigned* __restrict__ out)              // [NN*HH/2] packed bf16x2, normalized
{
    int w    = (blockIdx.x * 256 + threadIdx.x) >> 6;   // wave id
    int lane = threadIdx.x & 63;
    int half = lane >> 5;
    int l    = lane & 31;
    int row  = w * 2 + half;
    if (row >= NN) return;

    int e = head[row];
    float a0 = 0.f, a1 = 0.f, a2 = 0.f, a3 = 0.f;
    int cnt = 0;
    while (__any(e >= 0)) {
        if (e >= 0) {
            int2 n = node[e];                // (src, next)
            uint2 v = ((const uint2*)(xsrc + (size_t)n.x * HH))[l];
            a0 += bfbits2f((unsigned short)(v.x & 0xffffu));
            a1 += bfbits2f((unsigned short)(v.x >> 16));
            a2 += bfbits2f((unsigned short)(v.y & 0xffffu));
            a3 += bfbits2f((unsigned short)(v.y >> 16));
            ++cnt;
            e = n.y;
        }
    }
    float inv = 1.0f / fmaxf((float)cnt, 1.0f);
    unsigned p0 = ((unsigned)f2bfbits(a1 * inv) << 16) | f2bfbits(a0 * inv);
    unsigned p1 = ((unsigned)f2bfbits(a3 * inv) << 16) | f2bfbits(a2 * inv);
    ((uint2*)out)[(size_t)row * 32 + l] = make_uint2(p0, p1);
}

// ---------------------------------------------------------------------------
// SAGE GEMM + fused LN/ReLU/residual epilogue.
//   C = agg16A @ WlA^T + X @ WrA^T + blA   (+ agg16B @ WlB^T + X @ WrB^T + blB)
//   out = relu(LN(scale*C; g,b)) + X       (scale=0.5 when twoAgg)
// One wave = 16 rows x 128 cols; block = 4 waves.
// NOTE: X/agg16B rows are only ever read by the wave that writes the same
// rows of `out`, so out may alias X or agg16B (in-place) safely.
// ---------------------------------------------------------------------------
template<bool XF32>
__global__ __launch_bounds__(256) void sage_gemm(
    const unsigned short* __restrict__ agg16A,
    const unsigned short* __restrict__ WlA, const float* __restrict__ blA,
    const unsigned short* __restrict__ agg16B,
    const unsigned short* __restrict__ WlB, const float* __restrict__ blB,
    const void* __restrict__ X,       // root features = residual source
    const unsigned short* __restrict__ WrA, const unsigned short* __restrict__ WrB,
    const float* __restrict__ g, const float* __restrict__ bt,
    unsigned short* __restrict__ out, int twoAgg)
{
    const int lane = threadIdx.x & 63;
    const int wid  = threadIdx.x >> 6;
    const int m    = lane & 15;
    const int q    = lane >> 4;
    const int row0 = blockIdx.x * 64 + wid * 16;

    int arow = row0 + m;
    if (arow >= NN) arow = NN - 1;          // clamp loads; stores guarded

    f32x4 acc[8];
    for (int ct = 0; ct < 8; ++ct) acc[ct] = (f32x4){0.f, 0.f, 0.f, 0.f};

    for (int ks = 0; ks < 4; ++ks) {
        const int k0 = ks * 32 + q * 8;
        bf16x8 aR;
        if (XF32) {
            f32x4 r0 = *(const f32x4*)((const float*)X + (size_t)arow * HH + k0);
            f32x4 r1 = *(const f32x4*)((const float*)X + (size_t)arow * HH + k0 + 4);
            aR[0] = (short)f2bfbits(r0[0]); aR[1] = (short)f2bfbits(r0[1]);
            aR[2] = (short)f2bfbits(r0[2]); aR[3] = (short)f2bfbits(r0[3]);
            aR[4] = (short)f2bfbits(r1[0]); aR[5] = (short)f2bfbits(r1[1]);
            aR[6] = (short)f2bfbits(r1[2]); aR[7] = (short)f2bfbits(r1[3]);
        } else {
            aR = *(const bf16x8*)((const unsigned short*)X + (size_t)arow * HH + k0);
        }
        bf16x8 aA = *(const bf16x8*)(agg16A + (size_t)arow * HH + k0);
        bf16x8 aB = aR;
        if (twoAgg) aB = *(const bf16x8*)(agg16B + (size_t)arow * HH + k0);
        for (int ct = 0; ct < 8; ++ct) {
            const size_t wb = (size_t)((ct * 16 + m) * HH + k0);
            acc[ct] = __builtin_amdgcn_mfma_f32_16x16x32_bf16(
                aA, *(const bf16x8*)(WlA + wb), acc[ct], 0, 0, 0);
            acc[ct] = __builtin_amdgcn_mfma_f32_16x16x32_bf16(
                aR, *(const bf16x8*)(WrA + wb), acc[ct], 0, 0, 0);
            if (twoAgg) {
                acc[ct] = __builtin_amdgcn_mfma_f32_16x16x32_bf16(
                    aB, *(const bf16x8*)(WlB + wb), acc[ct], 0, 0, 0);
                acc[ct] = __builtin_amdgcn_mfma_f32_16x16x32_bf16(
                    aR, *(const bf16x8*)(WrB + wb), acc[ct], 0, 0, 0);
            }
        }
    }

    // -------- epilogue: bias -> (x0.5 if s) -> LN -> relu -> +residual --------
    const float scale = twoAgg ? 0.5f : 1.0f;
    float bias[8], gam[8], bet[8];
    for (int ct = 0; ct < 8; ++ct) {
        int j = ct * 16 + m;
        float bb = blA[j];
        if (twoAgg) bb += blB[j];
        bias[ct] = bb;
        gam[ct]  = g[j];
        bet[ct]  = bt[j];
    }
    float mu[4], rstd[4];
    for (int r = 0; r < 4; ++r) {
        float p = 0.f, p2 = 0.f;
        for (int ct = 0; ct < 8; ++ct) {
            float c = (acc[ct][r] + bias[ct]) * scale;
            acc[ct][r] = c;
            p += c; p2 += c * c;
        }
        for (int off = 1; off < 16; off <<= 1) {
            p  += __shfl_xor(p,  off);
            p2 += __shfl_xor(p2, off);
        }
        float mean = p * (1.0f / 128.0f);
        float var  = p2 * (1.0f / 128.0f) - mean * mean;
        mu[r]   = mean;
        rstd[r] = rsqrtf(var + 1e-5f);
    }
    for (int r = 0; r < 4; ++r) {
        int i = row0 + q * 4 + r;
        if (i >= NN) continue;
        for (int ct = 0; ct < 8; ++ct) {
            int j = ct * 16 + m;
            float v = (acc[ct][r] - mu[r]) * rstd[r] * gam[ct] + bet[ct];
            v = fmaxf(v, 0.f);
            float res = XF32 ? ((const float*)X)[(size_t)i * HH + j]
                             : bfbits2f(((const unsigned short*)X)[(size_t)i * HH + j]);
            out[(size_t)i * HH + j] = f2bfbits(v + res);
        }
    }
}

// ---------------------------------------------------------------------------
// Final projection: out = X @ Wout^T + bout   (NN x 64), fp32 output
// ---------------------------------------------------------------------------
__global__ __launch_bounds__(256) void final_proj(
    const unsigned short* __restrict__ X, const unsigned short* __restrict__ W,
    const float* __restrict__ bias, float* __restrict__ out)
{
    const int lane = threadIdx.x & 63;
    const int wid  = threadIdx.x >> 6;
    const int m    = lane & 15;
    const int q    = lane >> 4;
    const int row0 = blockIdx.x * 64 + wid * 16;
    int arow = row0 + m;
    if (arow >= NN) arow = NN - 1;

    f32x4 acc[4];
    for (int ct = 0; ct < 4; ++ct) acc[ct] = (f32x4){0.f, 0.f, 0.f, 0.f};

    for (int ks = 0; ks < 4; ++ks) {
        const int k0 = ks * 32 + q * 8;
        bf16x8 aR = *(const bf16x8*)(X + (size_t)arow * HH + k0);
        for (int ct = 0; ct < 4; ++ct) {
            const size_t wb = (size_t)((ct * 16 + m) * HH + k0);
            acc[ct] = __builtin_amdgcn_mfma_f32_16x16x32_bf16(
                aR, *(const bf16x8*)(W + wb), acc[ct], 0, 0, 0);
        }
    }
    for (int r = 0; r < 4; ++r) {
        int i = row0 + q * 4 + r;
        if (i >= NN) continue;
        for (int ct = 0; ct < 4; ++ct) {
            int j = ct * 16 + m;
            out[(size_t)i * OUTC + j] = acc[ct][r] + bias[j];
        }
    }
}

// ---------------------------------------------------------------------------
extern "C" void kernel_launch(void* const* d_in, const int* in_sizes, int n_in,
                              void* d_out, int out_size, void* d_ws, size_t ws_size,
                              hipStream_t stream)
{
    const float* xs  = (const float*)d_in[0];
    const float* xo  = (const float*)d_in[1];
    const float* xf  = (const float*)d_in[2];
    const int* ei0 = (const int*)d_in[3];
    const int* ei1 = (const int*)d_in[4];
    const int* ei2 = (const int*)d_in[5];
    const int* ei3 = (const int*)d_in[6];
    const float* Wl1 = (const float*)d_in[7];
    const float* bl1 = (const float*)d_in[8];
    const float* Wr1 = (const float*)d_in[9];
    const float* Wl2 = (const float*)d_in[10];
    const float* bl2 = (const float*)d_in[11];
    const float* Wr2 = (const float*)d_in[12];
    const float* lng = (const float*)d_in[13];
    const float* lnb = (const float*)d_in[14];
    const float* Wou = (const float*)d_in[15];
    const float* bou = (const float*)d_in[16];
    float* out = (float*)d_out;

    // workspace layout (16B aligned) — identical footprint to prior version
    char* ws = (char*)d_ws;
    const size_t xBytes = (size_t)NN * HH * 2;     // 25.6 MB (bf16)
    const int    WH     = HH * HH;                 // 16384
    unsigned short* aggA16 = (unsigned short*)ws; ws += xBytes;
    unsigned short* aggB16 = (unsigned short*)ws; ws += xBytes;  // doubles as xs16
    unsigned short* s1 = (unsigned short*)ws;     ws += xBytes;  // doubles as agg_t3
    unsigned short* o1 = (unsigned short*)ws;     ws += xBytes;  // doubles as xo16
    unsigned short* f1 = (unsigned short*)ws;     ws += xBytes;  // doubles as xf16
    int*  head = (int*)ws;  ws += (size_t)4 * NN * 4;   // 1.6 MB
    int2* node = (int2*)ws; ws += (size_t)4 * EE * 8;   // 19.2 MB
    unsigned short* Wl1b = (unsigned short*)ws; ws += (size_t)4 * WH * 2;
    unsigned short* Wr1b = (unsigned short*)ws; ws += (size_t)4 * WH * 2;
    unsigned short* Wl2b = (unsigned short*)ws; ws += (size_t)4 * WH * 2;
    unsigned short* Wr2b = (unsigned short*)ws; ws += (size_t)4 * WH * 2;
    unsigned short* Woub = (unsigned short*)ws; ws += (size_t)OUTC * HH * 2;

    unsigned short* xs16 = aggB16;   // dead after layer-1 t0/t2 gathers
    unsigned short* xo16 = o1;       // overwritten in place by o-gemm
    unsigned short* xf16 = f1;       // overwritten in place by f-gemm
    unsigned short* s2   = o1;       // o1 dead once layer-2 t1 gather is done

    const int egrid  = (4 * EE + 255) / 256;        // build
    const int ngrid2 = (((NN + 1) / 2) * 64 + 255) / 256; // gather: wave per 2 rows
    const int ggrid  = (NN + 63) / 64;              // gemm: 64 rows per block

    // ---- weights -> bf16 (reused 100k x) ----
    cvt_f32_bf16_v8<<<(4 * WH / 8 + 255) / 256, 256, 0, stream>>>(Wl1, Wl1b, 4 * WH / 8);
    cvt_f32_bf16_v8<<<(4 * WH / 8 + 255) / 256, 256, 0, stream>>>(Wr1, Wr1b, 4 * WH / 8);
    cvt_f32_bf16_v8<<<(4 * WH / 8 + 255) / 256, 256, 0, stream>>>(Wl2, Wl2b, 4 * WH / 8);
    cvt_f32_bf16_v8<<<(4 * WH / 8 + 255) / 256, 256, 0, stream>>>(Wr2, Wr2b, 4 * WH / 8);
    cvt_f32_bf16_v8<<<(OUTC * HH / 8 + 255) / 256, 256, 0, stream>>>(Wou, Woub, OUTC * HH / 8);

    // ---- inputs -> bf16 (into regions that die at the right time) ----
    const int nx8 = NN * HH / 8;
    cvt_f32_bf16_v8<<<(nx8 + 255) / 256, 256, 0, stream>>>(xs, xs16, nx8);
    cvt_f32_bf16_v8<<<(nx8 + 255) / 256, 256, 0, stream>>>(xo, xo16, nx8);
    cvt_f32_bf16_v8<<<(nx8 + 255) / 256, 256, 0, stream>>>(xf, xf16, nx8);

    // ---- adjacency build (all 4 edge types) ----
    hipMemsetAsync(head, 0xFF, (size_t)4 * NN * 4, stream);   // head = -1
    build_ll<<<egrid, 256, 0, stream>>>(ei0, ei1, ei2, ei3, head, node);

    // ---- layer 1: types 1,3 (outcome->study, facility->study) -> s1 first ----
    // (must run before o/f gemms destroy xo16/xf16; agg_t3 parks in s1 region)
    gather_ll2<<<ngrid2, 256, 0, stream>>>(head + 1 * NN, node, xo16, (unsigned*)aggA16);
    gather_ll2<<<ngrid2, 256, 0, stream>>>(head + 3 * NN, node, xf16, (unsigned*)s1);
    sage_gemm<true><<<ggrid, 256, 0, stream>>>(aggA16, Wl1b + 1 * WH, bl1 + 1 * HH,
        s1, Wl1b + 3 * WH, bl1 + 3 * HH,
        xs /*f32 residual*/, Wr1b + 1 * WH, Wr1b + 3 * WH, lng, lnb, s1, 1);

    // ---- layer 1: type 0 (study->outcome) -> o1 (in-place over xo16) ----
    gather_ll2<<<ngrid2, 256, 0, stream>>>(head + 0 * NN, node, xs16, (unsigned*)aggA16);
    sage_gemm<false><<<ggrid, 256, 0, stream>>>(aggA16, Wl1b + 0 * WH, bl1 + 0 * HH,
        nullptr, nullptr, nullptr,
        xo16, Wr1b + 0 * WH, nullptr, lng, lnb, o1, 0);

    // ---- layer 1: type 2 (study->facility) -> f1 (in-place over xf16) ----
    gather_ll2<<<ngrid2, 256, 0, stream>>>(head + 2 * NN, node, xs16, (unsigned*)aggA16);
    sage_gemm<false><<<ggrid, 256, 0, stream>>>(aggA16, Wl1b + 2 * WH, bl1 + 2 * HH,
        nullptr, nullptr, nullptr,
        xf16, Wr1b + 2 * WH, nullptr, lng, lnb, f1, 0);

    // ---- layer 2: only the study output feeds the final projection ----
    gather_ll2<<<ngrid2, 256, 0, stream>>>(head + 1 * NN, node, o1, (unsigned*)aggA16);
    gather_ll2<<<ngrid2, 256, 0, stream>>>(head + 3 * NN, node, f1, (unsigned*)aggB16);
    sage_gemm<false><<<ggrid, 256, 0, stream>>>(aggA16, Wl2b + 1 * WH, bl2 + 1 * HH,
        aggB16, Wl2b + 3 * WH, bl2 + 3 * HH,
        s1, Wr2b + 1 * WH, Wr2b + 3 * WH, lng + HH, lnb + HH, s2, 1);

    // ---- final projection (fp32 out) ----
    final_proj<<<ggrid, 256, 0, stream>>>(s2, Woub, bou, out);
}

// Round 2
// 722.626 us; speedup vs baseline: 1.4443x; 1.4443x over previous
//
#include <hip/hip_runtime.h>
#include <hip/hip_bf16.h>
#include <stdint.h>

#define NN   100000   // nodes per type
#define EE   600000   // edges per type
#define HH   128      // hidden
#define OUTC 64       // out channels

typedef __attribute__((ext_vector_type(8))) short bf16x8;   // 8 bf16 in 4 VGPRs
typedef __attribute__((ext_vector_type(4))) float f32x4;

__device__ __forceinline__ float bfbits2f(unsigned short b) {
    union { unsigned u; float f; } v; v.u = ((unsigned)b) << 16; return v.f;
}
__device__ __forceinline__ unsigned short f2bfbits(float f) {
    union { float f; unsigned u; } v; v.f = f;
    unsigned r = v.u + 0x7fffu + ((v.u >> 16) & 1u);   // RNE
    return (unsigned short)(r >> 16);
}

// ---------------------------------------------------------------------------
// Vectorized f32 -> bf16: 8 elems/thread (32B in, 16B out). n must be %8==0.
// ---------------------------------------------------------------------------
__global__ __launch_bounds__(256) void cvt_f32_bf16_v8(
    const float* __restrict__ in, unsigned short* __restrict__ out, int n8)
{
    int i = blockIdx.x * 256 + threadIdx.x;
    if (i >= n8) return;
    f32x4 a = ((const f32x4*)in)[(size_t)i * 2];
    f32x4 b = ((const f32x4*)in)[(size_t)i * 2 + 1];
    union { unsigned short us[8]; uint4 u4; } r;
    for (int j = 0; j < 4; ++j) { r.us[j] = f2bfbits(a[j]); r.us[4 + j] = f2bfbits(b[j]); }
    ((uint4*)out)[i] = r.u4;
}

// out[i] = bf16(a[i] + b[i]) — for combining Wr pairs: x@(WrA+WrB)^T
__global__ __launch_bounds__(256) void add2_cvt_v8(
    const float* __restrict__ a, const float* __restrict__ b,
    unsigned short* __restrict__ out, int n8)
{
    int i = blockIdx.x * 256 + threadIdx.x;
    if (i >= n8) return;
    f32x4 a0 = ((const f32x4*)a)[(size_t)i * 2];
    f32x4 a1 = ((const f32x4*)a)[(size_t)i * 2 + 1];
    f32x4 b0 = ((const f32x4*)b)[(size_t)i * 2];
    f32x4 b1 = ((const f32x4*)b)[(size_t)i * 2 + 1];
    union { unsigned short us[8]; uint4 u4; } r;
    for (int j = 0; j < 4; ++j) {
        r.us[j]     = f2bfbits(a0[j] + b0[j]);
        r.us[4 + j] = f2bfbits(a1[j] + b1[j]);
    }
    ((uint4*)out)[i] = r.u4;
}

// ---------------------------------------------------------------------------
// Linked-list adjacency build, all 4 edge types in one pass.
// ---------------------------------------------------------------------------
__global__ __launch_bounds__(256) void build_ll(
    const int* __restrict__ ei0, const int* __restrict__ ei1,
    const int* __restrict__ ei2, const int* __restrict__ ei3,
    int* __restrict__ head,      // [4*NN], pre-init to -1
    int2* __restrict__ node)     // [4*EE]
{
    int gid = blockIdx.x * 256 + threadIdx.x;
    if (gid >= 4 * EE) return;
    int t = gid / EE, e = gid - t * EE;
    const int* ei = (t == 0) ? ei0 : (t == 1) ? ei1 : (t == 2) ? ei2 : ei3;
    int src = ei[e];
    int dst = ei[EE + e];
    int prev = atomicExch(&head[t * NN + dst], gid);
    node[gid] = make_int2(src, prev);
}

// ---------------------------------------------------------------------------
// Gather-mean, bf16 source, FOUR rows per wave (16 lanes per row, uint4/lane).
// 4 independent list chases per wave-iteration quadruple the useful work per
// dependent node->row latency chain.
// ---------------------------------------------------------------------------
__global__ __launch_bounds__(256) void gather_ll4(
    const int* __restrict__ head,            // head + t*NN
    const int2* __restrict__ node,           // global edge-slot array
    const unsigned short* __restrict__ xsrc, // [NN*HH] bf16
    uint4* __restrict__ out)                 // [NN*HH/8] packed bf16, normalized
{
    int w    = (blockIdx.x * 256 + threadIdx.x) >> 6;   // wave id
    int lane = threadIdx.x & 63;
    int sub  = lane >> 4;          // 0..3: which row of the quad
    int l    = lane & 15;          // 16B chunk within row
    int row  = w * 4 + sub;
    if (row >= NN) return;

    int e = head[row];
    float a0=0.f,a1=0.f,a2=0.f,a3=0.f,a4=0.f,a5=0.f,a6=0.f,a7=0.f;
    int cnt = 0;
    while (__any(e >= 0)) {
        if (e >= 0) {
            int2 n = node[e];                // (src, next)
            uint4 v = ((const uint4*)(xsrc + (size_t)n.x * HH))[l];
            a0 += bfbits2f((unsigned short)(v.x & 0xffffu));
            a1 += bfbits2f((unsigned short)(v.x >> 16));
            a2 += bfbits2f((unsigned short)(v.y & 0xffffu));
            a3 += bfbits2f((unsigned short)(v.y >> 16));
            a4 += bfbits2f((unsigned short)(v.z & 0xffffu));
            a5 += bfbits2f((unsigned short)(v.z >> 16));
            a6 += bfbits2f((unsigned short)(v.w & 0xffffu));
            a7 += bfbits2f((unsigned short)(v.w >> 16));
            ++cnt;
            e = n.y;
        }
    }
    float inv = 1.0f / fmaxf((float)cnt, 1.0f);
    uint4 r;
    r.x = ((unsigned)f2bfbits(a1 * inv) << 16) | f2bfbits(a0 * inv);
    r.y = ((unsigned)f2bfbits(a3 * inv) << 16) | f2bfbits(a2 * inv);
    r.z = ((unsigned)f2bfbits(a5 * inv) << 16) | f2bfbits(a4 * inv);
    r.w = ((unsigned)f2bfbits(a7 * inv) << 16) | f2bfbits(a6 * inv);
    out[(size_t)row * 16 + l] = r;
}

// ---------------------------------------------------------------------------
// SAGE GEMM v2: LDS-resident weights + fused LN/ReLU/residual epilogue.
//   NMAT==3: C = aggA@WlA^T + Xb@Wrc^T + aggB@WlB^T  (Wrc = WrA+WrB), scale 0.5
//   NMAT==2: C = aggA@WlA^T + Xb@Wrc^T               (Wrc = WrA),     scale 1
//   out = relu(LN((C+bias)*scale; g,b)) + Xres
// Block = 512 threads (8 waves x 16 rows = 128 rows). Weights staged once per
// block into LDS with byte ^= (row&15)<<4 swizzle (<=4-way ds_read_b128).
// In-place out aliasing Xb/aggB is safe: each wave reads only its own rows
// before writing them; clamped tail reads are never stored.
// ---------------------------------------------------------------------------
template<int NMAT, bool XRESF32>
__global__ __launch_bounds__(512, NMAT == 2 ? 4 : 2) void sage_gemm2(
    const unsigned short* __restrict__ aggA,
    const unsigned short* __restrict__ aggB,     // null when NMAT==2
    const unsigned short* __restrict__ Xb,       // bf16 root features (MFMA A)
    const void* __restrict__ Xres,               // residual source (f32 or bf16)
    const float* __restrict__ blA, const float* __restrict__ blB,
    const unsigned short* __restrict__ WlA,
    const unsigned short* __restrict__ Wrc,
    const unsigned short* __restrict__ WlB,      // null when NMAT==2
    const float* __restrict__ g, const float* __restrict__ bt,
    unsigned short* __restrict__ out)
{
    __shared__ char wl[NMAT * 32768];

    // ---- stage weights (swizzled) ----
    for (int c = threadIdx.x; c < NMAT * 2048; c += 512) {
        int mat = c >> 11;
        int idx = c & 2047;
        int off = idx << 4;                    // byte offset within matrix
        int row = off >> 8;
        int swz = off ^ ((row & 15) << 4);
        const uint4* src = (mat == 0) ? (const uint4*)WlA
                         : (mat == 1) ? (const uint4*)Wrc
                                      : (const uint4*)WlB;
        *(uint4*)(wl + mat * 32768 + swz) = src[idx];
    }
    __syncthreads();

    const int lane = threadIdx.x & 63;
    const int wid  = threadIdx.x >> 6;         // 0..7
    const int m    = lane & 15;
    const int q    = lane >> 4;
    const int row0 = blockIdx.x * 128 + wid * 16;

    int arow = row0 + m;
    if (arow >= NN) arow = NN - 1;             // clamp loads; stores guarded

    // ---- preload A operands (all K) ----
    bf16x8 aA[4], aR[4], aB[4];
    for (int ks = 0; ks < 4; ++ks) {
        const int k0 = ks * 32 + q * 8;
        aA[ks] = *(const bf16x8*)(aggA + (size_t)arow * HH + k0);
        aR[ks] = *(const bf16x8*)(Xb   + (size_t)arow * HH + k0);
        if (NMAT == 3) aB[ks] = *(const bf16x8*)(aggB + (size_t)arow * HH + k0);
    }

    f32x4 acc[8];
    for (int ct = 0; ct < 8; ++ct) acc[ct] = (f32x4){0.f, 0.f, 0.f, 0.f};

#define LDW(mat, ct, ks) \
    (*(const bf16x8*)(wl + (mat) * 32768 + \
        (((((ct) * 16 + m) * 256) + (ks) * 64 + q * 16) ^ ((m & 15) << 4))))

    for (int ks = 0; ks < 4; ++ks) {
        for (int ct = 0; ct < 8; ++ct) {
            acc[ct] = __builtin_amdgcn_mfma_f32_16x16x32_bf16(
                aA[ks], LDW(0, ct, ks), acc[ct], 0, 0, 0);
            acc[ct] = __builtin_amdgcn_mfma_f32_16x16x32_bf16(
                aR[ks], LDW(1, ct, ks), acc[ct], 0, 0, 0);
            if (NMAT == 3)
                acc[ct] = __builtin_amdgcn_mfma_f32_16x16x32_bf16(
                    aB[ks], LDW(2, ct, ks), acc[ct], 0, 0, 0);
        }
    }
#undef LDW

    // -------- epilogue: bias -> (x0.5 if NMAT==3) -> LN -> relu -> +residual --
    const float scale = (NMAT == 3) ? 0.5f : 1.0f;
    float bias[8], gam[8], bet[8];
    for (int ct = 0; ct < 8; ++ct) {
        int j = ct * 16 + m;
        float bb = blA[j];
        if (NMAT == 3) bb += blB[j];
        bias[ct] = bb;
        gam[ct]  = g[j];
        bet[ct]  = bt[j];
    }
    float mu[4], rstd[4];
    for (int r = 0; r < 4; ++r) {
        float p = 0.f, p2 = 0.f;
        for (int ct = 0; ct < 8; ++ct) {
            float c = (acc[ct][r] + bias[ct]) * scale;
            acc[ct][r] = c;
            p += c; p2 += c * c;
        }
        for (int off = 1; off < 16; off <<= 1) {
            p  += __shfl_xor(p,  off);
            p2 += __shfl_xor(p2, off);
        }
        float mean = p * (1.0f / 128.0f);
        float var  = p2 * (1.0f / 128.0f) - mean * mean;
        mu[r]   = mean;
        rstd[r] = rsqrtf(var + 1e-5f);
    }
    for (int r = 0; r < 4; ++r) {
        int i = row0 + q * 4 + r;
        if (i >= NN) continue;
        for (int ct = 0; ct < 8; ++ct) {
            int j = ct * 16 + m;
            float v = (acc[ct][r] - mu[r]) * rstd[r] * gam[ct] + bet[ct];
            v = fmaxf(v, 0.f);
            float res = XRESF32 ? ((const float*)Xres)[(size_t)i * HH + j]
                                : bfbits2f(((const unsigned short*)Xres)[(size_t)i * HH + j]);
            out[(size_t)i * HH + j] = f2bfbits(v + res);
        }
    }
}

// ---------------------------------------------------------------------------
// Final projection with LDS-staged weight: out = X @ Wout^T + bout, fp32 out.
// ---------------------------------------------------------------------------
__global__ __launch_bounds__(512, 4) void final_proj2(
    const unsigned short* __restrict__ X, const unsigned short* __restrict__ W,
    const float* __restrict__ bias, float* __restrict__ out)
{
    __shared__ char wl[16384];                  // 64x128 bf16
    for (int c = threadIdx.x; c < 1024; c += 512) {
        int off = c << 4;
        int row = off >> 8;
        int swz = off ^ ((row & 15) << 4);
        *(uint4*)(wl + swz) = ((const uint4*)W)[c];
    }
    __syncthreads();

    const int lane = threadIdx.x & 63;
    const int wid  = threadIdx.x >> 6;
    const int m    = lane & 15;
    const int q    = lane >> 4;
    const int row0 = blockIdx.x * 128 + wid * 16;
    int arow = row0 + m;
    if (arow >= NN) arow = NN - 1;

    bf16x8 aR[4];
    for (int ks = 0; ks < 4; ++ks) {
        const int k0 = ks * 32 + q * 8;
        aR[ks] = *(const bf16x8*)(X + (size_t)arow * HH + k0);
    }
    f32x4 acc[4];
    for (int ct = 0; ct < 4; ++ct) acc[ct] = (f32x4){0.f, 0.f, 0.f, 0.f};

    for (int ks = 0; ks < 4; ++ks) {
        for (int ct = 0; ct < 4; ++ct) {
            const int row = ct * 16 + m;
            const int byt = (row * 256 + ks * 64 + q * 16) ^ ((m & 15) << 4);
            acc[ct] = __builtin_amdgcn_mfma_f32_16x16x32_bf16(
                aR[ks], *(const bf16x8*)(wl + byt), acc[ct], 0, 0, 0);
        }
    }
    for (int r = 0; r < 4; ++r) {
        int i = row0 + q * 4 + r;
        if (i >= NN) continue;
        for (int ct = 0; ct < 4; ++ct) {
            int j = ct * 16 + m;
            out[(size_t)i * OUTC + j] = acc[ct][r] + bias[j];
        }
    }
}

// ---------------------------------------------------------------------------
extern "C" void kernel_launch(void* const* d_in, const int* in_sizes, int n_in,
                              void* d_out, int out_size, void* d_ws, size_t ws_size,
                              hipStream_t stream)
{
    const float* xs  = (const float*)d_in[0];
    const float* xo  = (const float*)d_in[1];
    const float* xf  = (const float*)d_in[2];
    const int* ei0 = (const int*)d_in[3];
    const int* ei1 = (const int*)d_in[4];
    const int* ei2 = (const int*)d_in[5];
    const int* ei3 = (const int*)d_in[6];
    const float* Wl1 = (const float*)d_in[7];
    const float* bl1 = (const float*)d_in[8];
    const float* Wr1 = (const float*)d_in[9];
    const float* Wl2 = (const float*)d_in[10];
    const float* bl2 = (const float*)d_in[11];
    const float* Wr2 = (const float*)d_in[12];
    const float* lng = (const float*)d_in[13];
    const float* lnb = (const float*)d_in[14];
    const float* Wou = (const float*)d_in[15];
    const float* bou = (const float*)d_in[16];
    float* out = (float*)d_out;

    // workspace layout (16B aligned)
    char* ws = (char*)d_ws;
    const size_t xBytes = (size_t)NN * HH * 2;     // 25.6 MB (bf16)
    const int    WH     = HH * HH;                 // 16384
    unsigned short* aggA16 = (unsigned short*)ws; ws += xBytes;
    unsigned short* aggB16 = (unsigned short*)ws; ws += xBytes;  // doubles as xs16
    unsigned short* s1 = (unsigned short*)ws;     ws += xBytes;  // doubles as agg_t3
    unsigned short* o1 = (unsigned short*)ws;     ws += xBytes;  // doubles as xo16
    unsigned short* f1 = (unsigned short*)ws;     ws += xBytes;  // doubles as xf16
    int*  head = (int*)ws;  ws += (size_t)4 * NN * 4;   // 1.6 MB
    int2* node = (int2*)ws; ws += (size_t)4 * EE * 8;   // 19.2 MB
    unsigned short* Wl1b = (unsigned short*)ws; ws += (size_t)4 * WH * 2;
    unsigned short* Wr1b = (unsigned short*)ws; ws += (size_t)4 * WH * 2;
    unsigned short* Wl2b = (unsigned short*)ws; ws += (size_t)4 * WH * 2;
    unsigned short* Wr1c = (unsigned short*)ws; ws += (size_t)WH * 2;
    unsigned short* Wr2c = (unsigned short*)ws; ws += (size_t)WH * 2;
    unsigned short* Woub = (unsigned short*)ws; ws += (size_t)OUTC * HH * 2;

    unsigned short* xs16 = aggB16;   // dead after layer-1 t0/t2 gathers
    unsigned short* xo16 = o1;       // overwritten in place by o-gemm
    unsigned short* xf16 = f1;       // overwritten in place by f-gemm
    unsigned short* s2   = o1;       // o1 dead once layer-2 t1 gather is done

    const int egrid  = (4 * EE + 255) / 256;               // build
    const int ngrid4 = ((NN + 3) / 4 * 64 + 255) / 256;    // gather: wave per 4 rows
    const int ggrid2 = (NN + 127) / 128;                   // gemm v2: 128 rows/block

    // ---- weights -> bf16 ----
    cvt_f32_bf16_v8<<<(4 * WH / 8 + 255) / 256, 256, 0, stream>>>(Wl1, Wl1b, 4 * WH / 8);
    cvt_f32_bf16_v8<<<(4 * WH / 8 + 255) / 256, 256, 0, stream>>>(Wr1, Wr1b, 4 * WH / 8);
    cvt_f32_bf16_v8<<<(4 * WH / 8 + 255) / 256, 256, 0, stream>>>(Wl2, Wl2b, 4 * WH / 8);
    cvt_f32_bf16_v8<<<(OUTC * HH / 8 + 255) / 256, 256, 0, stream>>>(Wou, Woub, OUTC * HH / 8);
    // combined Wr for the two-edge-type study updates: x@(Wr_1 + Wr_3)^T
    add2_cvt_v8<<<(WH / 8 + 255) / 256, 256, 0, stream>>>(Wr1 + 1 * WH, Wr1 + 3 * WH, Wr1c, WH / 8);
    add2_cvt_v8<<<(WH / 8 + 255) / 256, 256, 0, stream>>>(Wr2 + 1 * WH, Wr2 + 3 * WH, Wr2c, WH / 8);

    // ---- inputs -> bf16 (into regions that die at the right time) ----
    const int nx8 = NN * HH / 8;
    cvt_f32_bf16_v8<<<(nx8 + 255) / 256, 256, 0, stream>>>(xs, xs16, nx8);
    cvt_f32_bf16_v8<<<(nx8 + 255) / 256, 256, 0, stream>>>(xo, xo16, nx8);
    cvt_f32_bf16_v8<<<(nx8 + 255) / 256, 256, 0, stream>>>(xf, xf16, nx8);

    // ---- adjacency build (all 4 edge types) ----
    hipMemsetAsync(head, 0xFF, (size_t)4 * NN * 4, stream);   // head = -1
    build_ll<<<egrid, 256, 0, stream>>>(ei0, ei1, ei2, ei3, head, node);

    // ---- layer 1: types 1,3 (outcome->study, facility->study) -> s1 first ----
    gather_ll4<<<ngrid4, 256, 0, stream>>>(head + 1 * NN, node, xo16, (uint4*)aggA16);
    gather_ll4<<<ngrid4, 256, 0, stream>>>(head + 3 * NN, node, xf16, (uint4*)s1);
    sage_gemm2<3, true><<<ggrid2, 512, 0, stream>>>(
        aggA16, s1, xs16, xs, bl1 + 1 * HH, bl1 + 3 * HH,
        Wl1b + 1 * WH, Wr1c, Wl1b + 3 * WH, lng, lnb, s1);

    // ---- layer 1: type 0 (study->outcome) -> o1 (in-place over xo16) ----
    gather_ll4<<<ngrid4, 256, 0, stream>>>(head + 0 * NN, node, xs16, (uint4*)aggA16);
    sage_gemm2<2, false><<<ggrid2, 512, 0, stream>>>(
        aggA16, nullptr, xo16, xo16, bl1 + 0 * HH, nullptr,
        Wl1b + 0 * WH, Wr1b + 0 * WH, nullptr, lng, lnb, o1);

    // ---- layer 1: type 2 (study->facility) -> f1 (in-place over xf16) ----
    gather_ll4<<<ngrid4, 256, 0, stream>>>(head + 2 * NN, node, xs16, (uint4*)aggA16);
    sage_gemm2<2, false><<<ggrid2, 512, 0, stream>>>(
        aggA16, nullptr, xf16, xf16, bl1 + 2 * HH, nullptr,
        Wl1b + 2 * WH, Wr1b + 2 * WH, nullptr, lng, lnb, f1);

    // ---- layer 2: only the study output feeds the final projection ----
    gather_ll4<<<ngrid4, 256, 0, stream>>>(head + 1 * NN, node, o1, (uint4*)aggA16);
    gather_ll4<<<ngrid4, 256, 0, stream>>>(head + 3 * NN, node, f1, (uint4*)aggB16);
    sage_gemm2<3, false><<<ggrid2, 512, 0, stream>>>(
        aggA16, aggB16, s1, s1, bl2 + 1 * HH, bl2 + 3 * HH,
        Wl2b + 1 * WH, Wr2c, Wl2b + 3 * WH, lng + HH, lnb + HH, s2);

    // ---- final projection (fp32 out) ----
    final_proj2<<<ggrid2, 512, 0, stream>>>(s2, Woub, bou, out);
}